// Round 11
// baseline (265.293 us; speedup 1.0000x reference)
//
#include <hip/hip_runtime.h>
#include <hip/hip_bf16.h>

#define N_NODES 50000
#define N_EDGES 800000
#define IN_C 128
#define HC 128
#define HEADS 8
#define NEG_SLOPE 0.2f
#define LN_EPS 1e-5f

#define LDH 136                 // per-wave h-tile row stride (128 + 8 pad)
#define ELL_CAP 64              // slots per node; max degree ~40 (Poisson 16)
#define GEMM_BLOCKS 782
#define FILL_BLOCKS 782
#define FUSED_BLOCKS (GEMM_BLOCKS + FILL_BLOCKS)   // 1564, R3 champion form

typedef __hip_bfloat16 bf16;
typedef __attribute__((ext_vector_type(8))) short short8;
typedef __attribute__((ext_vector_type(4))) float f32x4;

__device__ __forceinline__ float b2f(bf16 v) { return __bfloat162float(v); }

// float -> bf16 bits, round-to-nearest-even
__device__ __forceinline__ unsigned short f2bf(float f) {
    unsigned u = __float_as_uint(f);
    return (unsigned short)((u + 0x7fffu + ((u >> 16) & 1u)) >> 16);
}
__device__ __forceinline__ float bf2f(unsigned s) {
    return __uint_as_float(s << 16);
}
__device__ __forceinline__ short8 pack8(float4 u, float4 v) {
    short8 r;
    r[0] = (short)f2bf(u.x); r[1] = (short)f2bf(u.y);
    r[2] = (short)f2bf(u.z); r[3] = (short)f2bf(u.w);
    r[4] = (short)f2bf(v.x); r[5] = (short)f2bf(v.y);
    r[6] = (short)f2bf(v.z); r[7] = (short)f2bf(v.w);
    return r;
}

// ---------------------------------------------------------------------------
// prep: W -> Wt (bf16 transposed) AND zero cnt + cnt2 (probe scratch).
// ---------------------------------------------------------------------------
__global__ __launch_bounds__(256) void prep(
    const float* __restrict__ W, unsigned short* __restrict__ Wt,
    int* __restrict__ cnt, int* __restrict__ cnt2)
{
    int id = blockIdx.x * 256 + threadIdx.x;   // 64 blocks * 256 = 16384
    int k = id >> 7, n = id & 127;
    Wt[n * 128 + k] = f2bf(W[id]);
#pragma unroll
    for (int i = 0; i < 4; ++i) {
        int j = id + i * 16384;
        if (j < N_NODES) { cnt[j] = 0; cnt2[j] = 0; }
    }
}

// ---------------------------------------------------------------------------
// GEMM half, shared by fused and gemm_probe.
// ---------------------------------------------------------------------------
__device__ __forceinline__ void gemm_body(
    int gid, int t,
    const float* __restrict__ x, const unsigned short* __restrict__ Wt,
    const float* __restrict__ att_src, const float* __restrict__ att_dst,
    unsigned short* __restrict__ h_out,
    float* __restrict__ a_src, float* __restrict__ a_dst,
    short (*sH)[16 * LDH])
{
    const int wv  = t >> 6;
    const int l   = t & 63;
    const int gw  = gid * 4 + wv;
    if (gw >= N_NODES / 16) return;            // 3125 active waves, no barriers

    const int n0   = gw * 16;
    const int mrow = l & 15;
    const int quad = l >> 4;

    short8 afrag[4];
    const float* xr = x + (size_t)(n0 + mrow) * IN_C + quad * 8;
#pragma unroll
    for (int ko = 0; ko < 4; ++ko) {
        float4 u = *reinterpret_cast<const float4*>(xr + ko * 32);
        float4 v = *reinterpret_cast<const float4*>(xr + ko * 32 + 4);
        afrag[ko] = pack8(u, v);
    }

    f32x4 acc[8];
#pragma unroll
    for (int nt = 0; nt < 8; ++nt) acc[nt] = (f32x4)0.f;
#pragma unroll
    for (int nt = 0; nt < 8; ++nt) {
        const unsigned short* wr = Wt + (nt * 16 + mrow) * 128 + quad * 8;
#pragma unroll
        for (int ko = 0; ko < 4; ++ko) {
            short8 bfr = *reinterpret_cast<const short8*>(wr + ko * 32);
            acc[nt] = __builtin_amdgcn_mfma_f32_16x16x32_bf16(afrag[ko], bfr, acc[nt], 0, 0, 0);
        }
    }

    // C -> per-wave LDS tile. C/D layout: col = lane&15, row = quad*4 + r.
#pragma unroll
    for (int nt = 0; nt < 8; ++nt)
#pragma unroll
        for (int r = 0; r < 4; ++r)
            sH[wv][(quad * 4 + r) * LDH + nt * 16 + mrow] = (short)f2bf(acc[nt][r]);
    // within-wave LDS write->read: lockstep + compiler lgkmcnt, no barrier

    // h store: 16 rows x 128 cols bf16, 16B per lane per iter
#pragma unroll
    for (int i = 0; i < 4; ++i) {
        int row = i * 4 + (l >> 4);
        int col = (l & 15) * 8;
        short8 hv = *reinterpret_cast<const short8*>(&sH[wv][row * LDH + col]);
        *reinterpret_cast<short8*>(h_out + (size_t)(n0 + row) * HC + col) = hv;
    }

    // a_src/a_dst: 128 (node,head) pairs per wave, 2 per lane
#pragma unroll
    for (int pp = 0; pp < 2; ++pp) {
        int p  = l + pp * 64;
        int m  = p >> 3;
        int hd = p & 7;
        float ssum = 0.f, dsum = 0.f;
#pragma unroll
        for (int c = 0; c < 16; ++c) {
            float hv = bf2f((unsigned short)sH[wv][m * LDH + hd * 16 + c]);
            ssum = fmaf(hv, att_src[hd * 16 + c], ssum);
            dsum = fmaf(hv, att_dst[hd * 16 + c], dsum);
        }
        a_src[(n0 + m) * HEADS + hd] = ssum;
        a_dst[(n0 + m) * HEADS + hd] = dsum;
    }
}

// ---------------------------------------------------------------------------
// Fill half, shared by fused and fill_probe.
// ---------------------------------------------------------------------------
__device__ __forceinline__ void fill_body(
    int fid, int t,
    const int* __restrict__ ei, const float* __restrict__ edge_attr,
    int* __restrict__ cnt, unsigned int* __restrict__ ellp)
{
    const int e0 = (fid * 256 + t) * 4;
    if (e0 >= N_EDGES) return;
    // 800000 % 4 == 0 and e0 multiple of 4 -> all 4 edges valid
    const int4   s4 = *reinterpret_cast<const int4*>(ei + e0);
    const int4   d4 = *reinterpret_cast<const int4*>(ei + N_EDGES + e0);
    const float4 a4 = *reinterpret_cast<const float4*>(edge_attr + e0);

    int p0 = atomicAdd(&cnt[d4.x], 1);
    int p1 = atomicAdd(&cnt[d4.y], 1);
    int p2 = atomicAdd(&cnt[d4.z], 1);
    int p3 = atomicAdd(&cnt[d4.w], 1);
#define PUT(P, D, S, A)                                                    \
    if ((P) < ELL_CAP)                                                     \
        __builtin_nontemporal_store(                                       \
            (((unsigned)(S)) << 16) | (unsigned)f2bf(A),                   \
            &ellp[((D) << 6) + (P)]);
    PUT(p0, d4.x, s4.x, a4.x)
    PUT(p1, d4.y, s4.y, a4.y)
    PUT(p2, d4.z, s4.z, a4.z)
    PUT(p3, d4.w, s4.w, a4.w)
#undef PUT
}

// ---------------------------------------------------------------------------
// fused: R3 champion form — bid&1 interleaved GEMM/fill blocks.
// ---------------------------------------------------------------------------
__global__ __launch_bounds__(256) void fused(
    const float* __restrict__ x, const unsigned short* __restrict__ Wt,
    const float* __restrict__ att_src, const float* __restrict__ att_dst,
    const int* __restrict__ ei, const float* __restrict__ edge_attr,
    int* __restrict__ cnt, unsigned int* __restrict__ ellp,
    unsigned short* __restrict__ h_out,
    float* __restrict__ a_src, float* __restrict__ a_dst)
{
    __shared__ short sH[4][16 * LDH];          // 17408 B (gemm blocks only)
    const int bid = blockIdx.x;
    const int t   = threadIdx.x;
    if (bid & 1) {
        fill_body(bid >> 1, t, ei, edge_attr, cnt, ellp);
        return;
    }
    gemm_body(bid >> 1, t, x, Wt, att_src, att_dst, h_out, a_src, a_dst, sH);
}

// ---------------------------------------------------------------------------
// PROBES (attribution): standalone timings of each half.
// gemm_probe rewrites h/a_src/a_dst with byte-identical values (deterministic).
// fill_probe writes scratch cnt2/ellp2 carved from d_out (dead until gather).
// T_gemm + T_fill = total - 188us baseline; either >=~50us shows in top-5
// WITH its own counter row.
// ---------------------------------------------------------------------------
__global__ __launch_bounds__(256) void gemm_probe(
    const float* __restrict__ x, const unsigned short* __restrict__ Wt,
    const float* __restrict__ att_src, const float* __restrict__ att_dst,
    unsigned short* __restrict__ h_out,
    float* __restrict__ a_src, float* __restrict__ a_dst)
{
    __shared__ short sH[4][16 * LDH];
    gemm_body(blockIdx.x, threadIdx.x, x, Wt, att_src, att_dst,
              h_out, a_src, a_dst, sH);
}

__global__ __launch_bounds__(256) void fill_probe(
    const int* __restrict__ ei, const float* __restrict__ edge_attr,
    int* __restrict__ cnt2, unsigned int* __restrict__ ellp2)
{
    fill_body(blockIdx.x, threadIdx.x, ei, edge_attr, cnt2, ellp2);
}

// ---------------------------------------------------------------------------
// gather: byte-identical to the 188us champion.
// ---------------------------------------------------------------------------

// swizzle offset (j<<5)|24: lane' = (lane & 56) | j  (broadcast within the
// 8-lane head group; bit 5 preserved by per-32-lane ds_swizzle semantics)
#define LROW(CE, HV, J, OFF, B0)                                           \
    { int cj_ = __builtin_amdgcn_ds_swizzle((int)(CE), OFF);               \
      size_t r_ = ((B0) + (J) < cn) ? (size_t)(((unsigned)cj_) >> 16) : 0; \
      (HV)[J] = h2[r_ * 64 + l]; }
#define LOADROWS(CE, HV, B0)                                               \
    LROW(CE, HV, 0,  24, B0) LROW(CE, HV, 1,  56, B0)                      \
    LROW(CE, HV, 2,  88, B0) LROW(CE, HV, 3, 120, B0)                      \
    LROW(CE, HV, 4, 152, B0) LROW(CE, HV, 5, 184, B0)                      \
    LROW(CE, HV, 6, 216, B0) LROW(CE, HV, 7, 248, B0)

#define FROW(EV, HV, J, OFF)                                               \
    { float evj_ = __uint_as_float((unsigned)__builtin_amdgcn_ds_swizzle(  \
          __float_as_int(EV), OFF));                                       \
      acc0 = fmaf(evj_, b2f((HV)[J].x), acc0);                             \
      acc1 = fmaf(evj_, b2f((HV)[J].y), acc1); }
#define FMAROWS(EV, HV)                                                    \
    FROW(EV, HV, 0,  24) FROW(EV, HV, 1,  56) FROW(EV, HV, 2,  88)        \
    FROW(EV, HV, 3, 120) FROW(EV, HV, 4, 152) FROW(EV, HV, 5, 184)        \
    FROW(EV, HV, 6, 216) FROW(EV, HV, 7, 248)

__global__ __launch_bounds__(256) void gather_node(
    const int* __restrict__ cnt, const unsigned int* __restrict__ ellp,
    const float* __restrict__ a_src, const float* __restrict__ a_dst,
    const bf16* __restrict__ h,
    const float* __restrict__ x, const float* __restrict__ bvec,
    const float* __restrict__ gamma, const float* __restrict__ beta,
    const float* __restrict__ att_edge, const float* __restrict__ lin_w,
    const float* __restrict__ lin_b,
    float* __restrict__ out)
{
    const int wave = threadIdx.x >> 6;
    const int l    = threadIdx.x & 63;
    const int n    = blockIdx.x * 4 + wave;       // 50000 % 4 == 0
    const int hh   = l >> 3;
    const int jj   = l & 7;

    float ae0 = att_edge[2 * l], ae1 = att_edge[2 * l + 1];
    float p = ae0 * lin_w[2 * l] + ae1 * lin_w[2 * l + 1];
    float q = ae0 * lin_b[2 * l] + ae1 * lin_b[2 * l + 1];
#pragma unroll
    for (int off = 1; off <= 4; off <<= 1) {
        p += __shfl_xor(p, off, 64);
        q += __shfl_xor(q, off, 64);
    }
    const float2 bv = *reinterpret_cast<const float2*>(bvec + 2 * l);
    const float2 gv = *reinterpret_cast<const float2*>(gamma + 2 * l);
    const float2 be = *reinterpret_cast<const float2*>(beta + 2 * l);

    const float adq = a_dst[n * HEADS + hh] + q;
    const int   beg = n << 6;
    const int   cn  = min(cnt[n], ELL_CAP);

    float zp = 0.f, acc0 = 0.f, acc1 = 0.f;
    const __hip_bfloat162* h2 = reinterpret_cast<const __hip_bfloat162*>(h);

    if (cn > 0) {
        // pipeline prologue: chunk 0's ell word, a_src, and 8 h rows
        unsigned ce_c = ellp[beg + jj];
        float    as_c = a_src[(ce_c >> 16) * HEADS + hh];
        __hip_bfloat162 hv_c[8], hv_n[8];
        LOADROWS(ce_c, hv_c, 0)

        for (int bs = 0; ; bs += 8) {
            const unsigned ce   = ce_c;
            const float    as   = as_c;
            const bool     last = (bs + 8 >= cn);   // wave-uniform
            if (!last) {
                // issue next chunk's loads BEFORE this chunk's compute:
                // 8 h-rows + a_src stay in flight across the FMA block
                ce_c = ellp[beg + bs + 8 + jj];
                LOADROWS(ce_c, hv_n, bs + 8)
                as_c = a_src[(ce_c >> 16) * HEADS + hh];
            }
            const float ea = bf2f(ce & 0xffffu);
            float lg = fmaf(ea, p, as + adq);
            lg = fmaxf(lg, NEG_SLOPE * lg);         // leaky_relu, branchless
            const float ev = (bs + jj < cn) ? __expf(lg) : 0.f;
            zp += ev;
            FMAROWS(ev, hv_c)
            if (last) break;
#pragma unroll
            for (int j = 0; j < 8; ++j) hv_c[j] = hv_n[j];
        }
    }

    // z: reduce per-lane partials across the 8 lanes of this head group
    float z = zp;
    z += __shfl_xor(z, 1, 64);
    z += __shfl_xor(z, 2, 64);
    z += __shfl_xor(z, 4, 64);
    const float rz = 1.f / (z + 1e-16f);
    acc0 *= rz;
    acc1 *= rz;

    const size_t idx = (size_t)n * HC + 2 * l;
    const float2 xv = *reinterpret_cast<const float2*>(x + idx);
    float v0 = acc0 + xv.x + bv.x;
    float v1 = acc1 + xv.y + bv.y;
    float s1 = v0 + v1, s2 = v0 * v0 + v1 * v1;
#pragma unroll
    for (int off = 32; off >= 1; off >>= 1) {
        s1 += __shfl_xor(s1, off, 64);
        s2 += __shfl_xor(s2, off, 64);
    }
    const float mean = s1 * (1.f / HC);
    const float var  = s2 * (1.f / HC) - mean * mean;
    const float inv  = rsqrtf(var + LN_EPS);
    float y0 = (v0 - mean) * inv * gv.x + be.x;
    float y1 = (v1 - mean) * inv * gv.y + be.y;
    y0 = y0 > 0.f ? y0 : expm1f(y0);
    y1 = y1 > 0.f ? y1 : expm1f(y1);
    *reinterpret_cast<float2*>(out + idx) = make_float2(y0, y1);
}

// ---------------------------------------------------------------------------
extern "C" void kernel_launch(void* const* d_in, const int* in_sizes, int n_in,
                              void* d_out, int out_size, void* d_ws, size_t ws_size,
                              hipStream_t stream)
{
    const float* x         = (const float*)d_in[0];
    const int*   ei        = (const int*)d_in[1];
    const float* edge_attr = (const float*)d_in[2];
    const float* W         = (const float*)d_in[3];
    const float* b         = (const float*)d_in[4];
    const float* att_src   = (const float*)d_in[5];
    const float* att_dst   = (const float*)d_in[6];
    const float* att_edge  = (const float*)d_in[7];
    const float* lin_w     = (const float*)d_in[8];
    const float* lin_b     = (const float*)d_in[9];
    const float* gamma     = (const float*)d_in[10];
    const float* beta      = (const float*)d_in[11];

    char* ws = (char*)d_ws;
    bf16*  h     = (bf16*)ws;  ws += (size_t)N_NODES * HC * sizeof(bf16);      // 12.8 MB
    float* a_src = (float*)ws; ws += (size_t)N_NODES * HEADS * sizeof(float);  //  1.6 MB
    float* a_dst = (float*)ws; ws += (size_t)N_NODES * HEADS * sizeof(float);  //  1.6 MB
    int*   cnt   = (int*)ws;   ws += (size_t)N_NODES * sizeof(int);            //  0.2 MB
    unsigned short* Wt = (unsigned short*)ws;
    ws += (size_t)128 * 128 * sizeof(unsigned short);                          //  32 KB
    unsigned int* ellp = (unsigned int*)ws;
    ws += (size_t)(N_NODES * ELL_CAP + 64) * sizeof(unsigned int);             // 12.8 MB + pad

    // probe scratch carved from d_out (25.6 MB; dead until gather overwrites)
    int*          cnt2  = (int*)d_out;                                         //  0.2 MB
    unsigned int* ellp2 = (unsigned int*)((char*)d_out + (256 << 10));         // 12.8 MB

    prep<<<64, 256, 0, stream>>>(W, Wt, cnt, cnt2);

    fused<<<FUSED_BLOCKS, 256, 0, stream>>>(
        x, Wt, att_src, att_dst, ei, edge_attr, cnt, ellp,
        (unsigned short*)h, a_src, a_dst);

    gemm_probe<<<GEMM_BLOCKS, 256, 0, stream>>>(
        x, Wt, att_src, att_dst, (unsigned short*)h, a_src, a_dst);

    fill_probe<<<FILL_BLOCKS, 256, 0, stream>>>(ei, edge_attr, cnt2, ellp2);

    gather_node<<<N_NODES / 4, 256, 0, stream>>>(
        cnt, ellp, a_src, a_dst, h, x, b, gamma, beta,
        att_edge, lin_w, lin_b, (float*)d_out);
}

// Round 14
// 191.494 us; speedup vs baseline: 1.3854x; 1.3854x over previous
//
#include <hip/hip_runtime.h>
#include <hip/hip_bf16.h>

#define N_NODES 50000
#define N_EDGES 800000
#define IN_C 128
#define HC 128
#define HEADS 8
#define NEG_SLOPE 0.2f
#define LN_EPS 1e-5f

#define LDH 136                 // per-wave h-tile row stride (128 + 8 pad)
#define ELL_CAP 64              // slots per node; max degree ~40 (Poisson 16)
#define GEMM_BLOCKS 782
#define FILL_BLOCKS 782
#define FUSED_BLOCKS (GEMM_BLOCKS + FILL_BLOCKS)   // 1564, champion form
#define NBUCK 98                // dst buckets of 512 nodes (98*512 = 50176)
#define BCAP 26                 // arena slots per (bucket, block); lambda 10.45
#define OVF_CAP 4096            // global spill (expect ~0.2 entries total)

typedef __hip_bfloat16 bf16;
typedef __attribute__((ext_vector_type(8))) short short8;
typedef __attribute__((ext_vector_type(4))) float f32x4;
typedef unsigned long long u64;

__device__ __forceinline__ float b2f(bf16 v) { return __bfloat162float(v); }

// float -> bf16 bits, round-to-nearest-even
__device__ __forceinline__ unsigned short f2bf(float f) {
    unsigned u = __float_as_uint(f);
    return (unsigned short)((u + 0x7fffu + ((u >> 16) & 1u)) >> 16);
}
__device__ __forceinline__ float bf2f(unsigned s) {
    return __uint_as_float(s << 16);
}
__device__ __forceinline__ short8 pack8(float4 u, float4 v) {
    short8 r;
    r[0] = (short)f2bf(u.x); r[1] = (short)f2bf(u.y);
    r[2] = (short)f2bf(u.z); r[3] = (short)f2bf(u.w);
    r[4] = (short)f2bf(v.x); r[5] = (short)f2bf(v.y);
    r[6] = (short)f2bf(v.z); r[7] = (short)f2bf(v.w);
    return r;
}

// LDS layout for fused (union of the two roles)
union FusedSm {
    short sH[4][16 * LDH];                  // 17408 B (GEMM role)
    struct {                                // 20776 B (binA2 role)
        u64 recs[NBUCK][BCAP];
        int lcnt[NBUCK];
    } bin;
};

// ---------------------------------------------------------------------------
// prep: W (fp32,[k][n]) -> Wt (bf16,[n][k]); zero the 1-int overflow counter.
// cnt needs no zeroing (ebuild writes all nodes); bcnt written by every
// fill block unconditionally.
// ---------------------------------------------------------------------------
__global__ __launch_bounds__(256) void prep(
    const float* __restrict__ W, unsigned short* __restrict__ Wt,
    int* __restrict__ ovfc)
{
    int id = blockIdx.x * 256 + threadIdx.x;   // 64 blocks * 256 = 16384
    int k = id >> 7, n = id & 127;
    Wt[n * 128 + k] = f2bf(W[id]);
    if (id == 0) *ovfc = 0;
}

// ---------------------------------------------------------------------------
// GEMM half (measured 11us standalone, R11 probe) — unchanged.
// ---------------------------------------------------------------------------
__device__ __forceinline__ void gemm_body(
    int gid, int t,
    const float* __restrict__ x, const unsigned short* __restrict__ Wt,
    const float* __restrict__ att_src, const float* __restrict__ att_dst,
    unsigned short* __restrict__ h_out,
    float* __restrict__ a_src, float* __restrict__ a_dst,
    short (*sH)[16 * LDH])
{
    const int wv  = t >> 6;
    const int l   = t & 63;
    const int gw  = gid * 4 + wv;
    if (gw >= N_NODES / 16) return;            // 3125 active waves, no barriers

    const int n0   = gw * 16;
    const int mrow = l & 15;
    const int quad = l >> 4;

    short8 afrag[4];
    const float* xr = x + (size_t)(n0 + mrow) * IN_C + quad * 8;
#pragma unroll
    for (int ko = 0; ko < 4; ++ko) {
        float4 u = *reinterpret_cast<const float4*>(xr + ko * 32);
        float4 v = *reinterpret_cast<const float4*>(xr + ko * 32 + 4);
        afrag[ko] = pack8(u, v);
    }

    f32x4 acc[8];
#pragma unroll
    for (int nt = 0; nt < 8; ++nt) acc[nt] = (f32x4)0.f;
#pragma unroll
    for (int nt = 0; nt < 8; ++nt) {
        const unsigned short* wr = Wt + (nt * 16 + mrow) * 128 + quad * 8;
#pragma unroll
        for (int ko = 0; ko < 4; ++ko) {
            short8 bfr = *reinterpret_cast<const short8*>(wr + ko * 32);
            acc[nt] = __builtin_amdgcn_mfma_f32_16x16x32_bf16(afrag[ko], bfr, acc[nt], 0, 0, 0);
        }
    }

    // C -> per-wave LDS tile. C/D layout: col = lane&15, row = quad*4 + r.
#pragma unroll
    for (int nt = 0; nt < 8; ++nt)
#pragma unroll
        for (int r = 0; r < 4; ++r)
            sH[wv][(quad * 4 + r) * LDH + nt * 16 + mrow] = (short)f2bf(acc[nt][r]);
    // within-wave LDS write->read: lockstep + compiler lgkmcnt, no barrier

    // h store: 16 rows x 128 cols bf16, 16B per lane per iter
#pragma unroll
    for (int i = 0; i < 4; ++i) {
        int row = i * 4 + (l >> 4);
        int col = (l & 15) * 8;
        short8 hv = *reinterpret_cast<const short8*>(&sH[wv][row * LDH + col]);
        *reinterpret_cast<short8*>(h_out + (size_t)(n0 + row) * HC + col) = hv;
    }

    // a_src/a_dst: 128 (node,head) pairs per wave, 2 per lane
#pragma unroll
    for (int pp = 0; pp < 2; ++pp) {
        int p  = l + pp * 64;
        int m  = p >> 3;
        int hd = p & 7;
        float ssum = 0.f, dsum = 0.f;
#pragma unroll
        for (int c = 0; c < 16; ++c) {
            float hv = bf2f((unsigned short)sH[wv][m * LDH + hd * 16 + c]);
            ssum = fmaf(hv, att_src[hd * 16 + c], ssum);
            dsum = fmaf(hv, att_dst[hd * 16 + c], dsum);
        }
        a_src[(n0 + m) * HEADS + hd] = ssum;
        a_dst[(n0 + m) * HEADS + hd] = dsum;
    }
}

// ---------------------------------------------------------------------------
// fused: bid&1 split (champion form).
//   even -> GEMM. odd -> binA2: ZERO global atomics, ZERO contended counters.
//   Each fill block LDS-bins its 1024 edges into 98 dst-range buckets
//   (D>>9), clamps to BCAP (overflow -> tiny spill list), writes each run
//   to its STATIC arena segment arena[bucket][blk][26] + one coalesced
//   196B bcnt row. R11 probe showed the old fill's 65us = 800k partial-line
//   global RMWs (WRITE 50.3MB = 800k x 64B); R10 showed shared reservation
//   counters serialize (782-way). Static segments avoid both.
// ---------------------------------------------------------------------------
__global__ __launch_bounds__(256) void fused(
    const float* __restrict__ x, const unsigned short* __restrict__ Wt,
    const float* __restrict__ att_src, const float* __restrict__ att_dst,
    const int* __restrict__ ei, const float* __restrict__ edge_attr,
    u64* __restrict__ arena, unsigned short* __restrict__ bcnt,
    int* __restrict__ ovfc, u64* __restrict__ ovf,
    unsigned short* __restrict__ h_out,
    float* __restrict__ a_src, float* __restrict__ a_dst)
{
    __shared__ FusedSm sm;
    const int bid = blockIdx.x;
    const int t   = threadIdx.x;

    if (bid & 1) {
        // ---------------- binA2 ----------------
        const int blk = bid >> 1;              // 0..781
        if (t < NBUCK) sm.bin.lcnt[t] = 0;
        __syncthreads();

        const int e0 = blk * 1024 + t * 4;
        if (e0 < N_EDGES) {                    // N_EDGES%4==0 -> int4 safe
            const int4   s4 = *reinterpret_cast<const int4*>(ei + e0);
            const int4   d4 = *reinterpret_cast<const int4*>(ei + N_EDGES + e0);
            const float4 a4 = *reinterpret_cast<const float4*>(edge_attr + e0);
#define BIN1(D, S, A)                                                      \
            {                                                              \
                const unsigned w_ =                                        \
                    (((unsigned)(S)) << 16) | (unsigned)f2bf(A);           \
                const int b_ = (D) >> 9;                                   \
                int p_ = atomicAdd(&sm.bin.lcnt[b_], 1);                   \
                if (p_ < BCAP)                                             \
                    sm.bin.recs[b_][p_] =                                  \
                        ((u64)(unsigned)((D) & 511) << 32) | (u64)w_;      \
                else {                                                     \
                    int op_ = atomicAdd(ovfc, 1);                          \
                    if (op_ < OVF_CAP)                                     \
                        ovf[op_] = ((u64)(unsigned)(D) << 32) | (u64)w_;   \
                }                                                          \
            }
            BIN1(d4.x, s4.x, a4.x)
            BIN1(d4.y, s4.y, a4.y)
            BIN1(d4.z, s4.z, a4.z)
            BIN1(d4.w, s4.w, a4.w)
#undef BIN1
        }
        __syncthreads();
        if (t < NBUCK) {
            int k = min(sm.bin.lcnt[t], BCAP);
            sm.bin.lcnt[t] = k;                // clamp for copy loop
            bcnt[blk * NBUCK + t] = (unsigned short)k;   // coalesced 196B row
        }
        __syncthreads();
        // LDS runs -> static arena segments (bucket-major for ebuild)
        for (int i = t; i < NBUCK * BCAP; i += 256) {
            const int bi = i / BCAP;
            const int j  = i - bi * BCAP;
            if (j < sm.bin.lcnt[bi])
                arena[((size_t)bi * FILL_BLOCKS + blk) * BCAP + j] =
                    sm.bin.recs[bi][j];
        }
        return;
    }

    gemm_body(bid >> 1, t, x, Wt, att_src, att_dst, h_out, a_src, a_dst, sm.sH);
}

// ---------------------------------------------------------------------------
// ebuild: 98 blocks x 1024 threads, one bucket each. Linear coalesced scan
// of the bucket's contiguous segment array (arena + b*782*26, 159KB; valid
// prefix per segment via bcnt), ELL slots via 512 LDS cursors (~16-way),
// ellp/cnt written with NORMAL stores — one block owns a bucket's entire
// ellp region, so every line has a single writer (no cross-XCD ping-pong,
// no partial-line memory RMW storm).
// ---------------------------------------------------------------------------
__global__ __launch_bounds__(1024) void ebuild(
    const u64* __restrict__ arena, const unsigned short* __restrict__ bcnt,
    const int* __restrict__ ovfc, const u64* __restrict__ ovf,
    unsigned int* __restrict__ ellp, int* __restrict__ cnt)
{
    __shared__ int lc[512];
    __shared__ unsigned short sbc[FILL_BLOCKS];
    const int t = threadIdx.x;
    const int b = blockIdx.x;                  // bucket 0..97
    if (t < 512) lc[t] = 0;
    if (t < FILL_BLOCKS) sbc[t] = bcnt[t * NBUCK + b];
    __syncthreads();

    const u64* seg = arena + (size_t)b * (FILL_BLOCKS * BCAP);
    for (int q = t; q < FILL_BLOCKS * BCAP; q += 1024) {
        const int blk = q / BCAP;
        const int sl  = q - blk * BCAP;
        if (sl < (int)sbc[blk]) {
            const u64 rec = seg[q];            // coalesced: linear in q
            const int dl = (int)(rec >> 32);   // 0..511
            int p = atomicAdd(&lc[dl], 1);
            if (p < ELL_CAP)
                ellp[((size_t)((b << 9) + dl) << 6) + p] = (unsigned)rec;
        }
    }
    // spill entries (expected ~0; cap 4096): every block scans, keeps its own
    const int ovn = min(*ovfc, OVF_CAP);
    for (int q = t; q < ovn; q += 1024) {
        const u64 rec = ovf[q];
        const int n = (int)(rec >> 32);
        if ((n >> 9) == b) {
            int p = atomicAdd(&lc[n & 511], 1);
            if (p < ELL_CAP)
                ellp[((size_t)n << 6) + p] = (unsigned)rec;
        }
    }
    __syncthreads();
    if (t < 512) {
        const int n = (b << 9) + t;
        if (n < N_NODES) cnt[n] = min(lc[t], ELL_CAP);
    }
}

// ---------------------------------------------------------------------------
// gather: byte-identical to the 188us champion.
// ---------------------------------------------------------------------------

// swizzle offset (j<<5)|24: lane' = (lane & 56) | j  (broadcast within the
// 8-lane head group; bit 5 preserved by per-32-lane ds_swizzle semantics)
#define LROW(CE, HV, J, OFF, B0)                                           \
    { int cj_ = __builtin_amdgcn_ds_swizzle((int)(CE), OFF);               \
      size_t r_ = ((B0) + (J) < cn) ? (size_t)(((unsigned)cj_) >> 16) : 0; \
      (HV)[J] = h2[r_ * 64 + l]; }
#define LOADROWS(CE, HV, B0)                                               \
    LROW(CE, HV, 0,  24, B0) LROW(CE, HV, 1,  56, B0)                      \
    LROW(CE, HV, 2,  88, B0) LROW(CE, HV, 3, 120, B0)                      \
    LROW(CE, HV, 4, 152, B0) LROW(CE, HV, 5, 184, B0)                      \
    LROW(CE, HV, 6, 216, B0) LROW(CE, HV, 7, 248, B0)

#define FROW(EV, HV, J, OFF)                                               \
    { float evj_ = __uint_as_float((unsigned)__builtin_amdgcn_ds_swizzle(  \
          __float_as_int(EV), OFF));                                       \
      acc0 = fmaf(evj_, b2f((HV)[J].x), acc0);                             \
      acc1 = fmaf(evj_, b2f((HV)[J].y), acc1); }
#define FMAROWS(EV, HV)                                                    \
    FROW(EV, HV, 0,  24) FROW(EV, HV, 1,  56) FROW(EV, HV, 2,  88)        \
    FROW(EV, HV, 3, 120) FROW(EV, HV, 4, 152) FROW(EV, HV, 5, 184)        \
    FROW(EV, HV, 6, 216) FROW(EV, HV, 7, 248)

__global__ __launch_bounds__(256) void gather_node(
    const int* __restrict__ cnt, const unsigned int* __restrict__ ellp,
    const float* __restrict__ a_src, const float* __restrict__ a_dst,
    const bf16* __restrict__ h,
    const float* __restrict__ x, const float* __restrict__ bvec,
    const float* __restrict__ gamma, const float* __restrict__ beta,
    const float* __restrict__ att_edge, const float* __restrict__ lin_w,
    const float* __restrict__ lin_b,
    float* __restrict__ out)
{
    const int wave = threadIdx.x >> 6;
    const int l    = threadIdx.x & 63;
    const int n    = blockIdx.x * 4 + wave;       // 50000 % 4 == 0
    const int hh   = l >> 3;
    const int jj   = l & 7;

    float ae0 = att_edge[2 * l], ae1 = att_edge[2 * l + 1];
    float p = ae0 * lin_w[2 * l] + ae1 * lin_w[2 * l + 1];
    float q = ae0 * lin_b[2 * l] + ae1 * lin_b[2 * l + 1];
#pragma unroll
    for (int off = 1; off <= 4; off <<= 1) {
        p += __shfl_xor(p, off, 64);
        q += __shfl_xor(q, off, 64);
    }
    const float2 bv = *reinterpret_cast<const float2*>(bvec + 2 * l);
    const float2 gv = *reinterpret_cast<const float2*>(gamma + 2 * l);
    const float2 be = *reinterpret_cast<const float2*>(beta + 2 * l);

    const float adq = a_dst[n * HEADS + hh] + q;
    const int   beg = n << 6;
    const int   cn  = min(cnt[n], ELL_CAP);

    float zp = 0.f, acc0 = 0.f, acc1 = 0.f;
    const __hip_bfloat162* h2 = reinterpret_cast<const __hip_bfloat162*>(h);

    if (cn > 0) {
        // pipeline prologue: chunk 0's ell word, a_src, and 8 h rows
        unsigned ce_c = ellp[beg + jj];
        float    as_c = a_src[(ce_c >> 16) * HEADS + hh];
        __hip_bfloat162 hv_c[8], hv_n[8];
        LOADROWS(ce_c, hv_c, 0)

        for (int bs = 0; ; bs += 8) {
            const unsigned ce   = ce_c;
            const float    as   = as_c;
            const bool     last = (bs + 8 >= cn);   // wave-uniform
            if (!last) {
                // issue next chunk's loads BEFORE this chunk's compute:
                // 8 h-rows + a_src stay in flight across the FMA block
                ce_c = ellp[beg + bs + 8 + jj];
                LOADROWS(ce_c, hv_n, bs + 8)
                as_c = a_src[(ce_c >> 16) * HEADS + hh];
            }
            const float ea = bf2f(ce & 0xffffu);
            float lg = fmaf(ea, p, as + adq);
            lg = fmaxf(lg, NEG_SLOPE * lg);         // leaky_relu, branchless
            const float ev = (bs + jj < cn) ? __expf(lg) : 0.f;
            zp += ev;
            FMAROWS(ev, hv_c)
            if (last) break;
#pragma unroll
            for (int j = 0; j < 8; ++j) hv_c[j] = hv_n[j];
        }
    }

    // z: reduce per-lane partials across the 8 lanes of this head group
    float z = zp;
    z += __shfl_xor(z, 1, 64);
    z += __shfl_xor(z, 2, 64);
    z += __shfl_xor(z, 4, 64);
    const float rz = 1.f / (z + 1e-16f);
    acc0 *= rz;
    acc1 *= rz;

    const size_t idx = (size_t)n * HC + 2 * l;
    const float2 xv = *reinterpret_cast<const float2*>(x + idx);
    float v0 = acc0 + xv.x + bv.x;
    float v1 = acc1 + xv.y + bv.y;
    float s1 = v0 + v1, s2 = v0 * v0 + v1 * v1;
#pragma unroll
    for (int off = 32; off >= 1; off >>= 1) {
        s1 += __shfl_xor(s1, off, 64);
        s2 += __shfl_xor(s2, off, 64);
    }
    const float mean = s1 * (1.f / HC);
    const float var  = s2 * (1.f / HC) - mean * mean;
    const float inv  = rsqrtf(var + LN_EPS);
    float y0 = (v0 - mean) * inv * gv.x + be.x;
    float y1 = (v1 - mean) * inv * gv.y + be.y;
    y0 = y0 > 0.f ? y0 : expm1f(y0);
    y1 = y1 > 0.f ? y1 : expm1f(y1);
    *reinterpret_cast<float2*>(out + idx) = make_float2(y0, y1);
}

// ---------------------------------------------------------------------------
extern "C" void kernel_launch(void* const* d_in, const int* in_sizes, int n_in,
                              void* d_out, int out_size, void* d_ws, size_t ws_size,
                              hipStream_t stream)
{
    const float* x         = (const float*)d_in[0];
    const int*   ei        = (const int*)d_in[1];
    const float* edge_attr = (const float*)d_in[2];
    const float* W         = (const float*)d_in[3];
    const float* b         = (const float*)d_in[4];
    const float* att_src   = (const float*)d_in[5];
    const float* att_dst   = (const float*)d_in[6];
    const float* att_edge  = (const float*)d_in[7];
    const float* lin_w     = (const float*)d_in[8];
    const float* lin_b     = (const float*)d_in[9];
    const float* gamma     = (const float*)d_in[10];
    const float* beta      = (const float*)d_in[11];

    char* ws = (char*)d_ws;
    bf16*  h     = (bf16*)ws;  ws += (size_t)N_NODES * HC * sizeof(bf16);      // 12.8 MB
    float* a_src = (float*)ws; ws += (size_t)N_NODES * HEADS * sizeof(float);  //  1.6 MB
    float* a_dst = (float*)ws; ws += (size_t)N_NODES * HEADS * sizeof(float);  //  1.6 MB
    int*   cnt   = (int*)ws;   ws += (size_t)N_NODES * sizeof(int);            //  0.2 MB
    unsigned short* Wt = (unsigned short*)ws;
    ws += (size_t)128 * 128 * sizeof(unsigned short);                          //  32 KB
    unsigned int* ellp = (unsigned int*)ws;
    ws += (size_t)(N_NODES * ELL_CAP + 64) * sizeof(unsigned int);             // 12.8 MB + pad
    unsigned short* bcnt = (unsigned short*)ws;
    ws += (size_t)FILL_BLOCKS * NBUCK * sizeof(unsigned short);                // 153 KB
    int* ovfc = (int*)ws;      ws += 64;                                       // 64 B (pad)
    u64* ovf  = (u64*)ws;      ws += (size_t)OVF_CAP * sizeof(u64);            //  32 KB
    // arena (16 MB) lives in d_out (25.6 MB): consumed by ebuild BEFORE
    // gather overwrites d_out with the real output.
    u64* arena = (u64*)d_out;

    prep<<<64, 256, 0, stream>>>(W, Wt, ovfc);

    fused<<<FUSED_BLOCKS, 256, 0, stream>>>(
        x, Wt, att_src, att_dst, ei, edge_attr, arena, bcnt, ovfc, ovf,
        (unsigned short*)h, a_src, a_dst);

    ebuild<<<NBUCK, 1024, 0, stream>>>(arena, bcnt, ovfc, ovf, ellp, cnt);

    gather_node<<<N_NODES / 4, 256, 0, stream>>>(
        cnt, ellp, a_src, a_dst, h, x, b, gamma, beta,
        att_edge, lin_w, lin_b, (float*)d_out);
}

// Round 15
// 191.397 us; speedup vs baseline: 1.3861x; 1.0005x over previous
//
#include <hip/hip_runtime.h>
#include <hip/hip_bf16.h>

#define N_NODES 50000
#define N_EDGES 800000
#define IN_C 128
#define HC 128
#define HEADS 8
#define NEG_SLOPE 0.2f
#define LN_EPS 1e-5f

#define LDH 136                 // per-wave h-tile row stride (128 + 8 pad)
#define ELL_CAP 64              // slots per node; max degree ~40 (Poisson 16)
#define GEMM_BLOCKS 782
#define FILL_BLOCKS 782
#define FUSED_BLOCKS (GEMM_BLOCKS + FILL_BLOCKS)   // 1564, champion form
#define NBUCK 392               // dst buckets of 128 nodes (392*128 = 50176)
#define BCAP 8                  // segment = exactly one 64B line; lambda 2.6
#define OVF_CAP 8192            // global spill (expect ~460 entries)
#define SENT 0xFFFFFFFFFFFFFFFFull

typedef __hip_bfloat16 bf16;
typedef __attribute__((ext_vector_type(8))) short short8;
typedef __attribute__((ext_vector_type(4))) float f32x4;
typedef unsigned long long u64;

__device__ __forceinline__ float b2f(bf16 v) { return __bfloat162float(v); }

// float -> bf16 bits, round-to-nearest-even
__device__ __forceinline__ unsigned short f2bf(float f) {
    unsigned u = __float_as_uint(f);
    return (unsigned short)((u + 0x7fffu + ((u >> 16) & 1u)) >> 16);
}
__device__ __forceinline__ float bf2f(unsigned s) {
    return __uint_as_float(s << 16);
}
__device__ __forceinline__ short8 pack8(float4 u, float4 v) {
    short8 r;
    r[0] = (short)f2bf(u.x); r[1] = (short)f2bf(u.y);
    r[2] = (short)f2bf(u.z); r[3] = (short)f2bf(u.w);
    r[4] = (short)f2bf(v.x); r[5] = (short)f2bf(v.y);
    r[6] = (short)f2bf(v.z); r[7] = (short)f2bf(v.w);
    return r;
}

// LDS layout for fused (union of the two roles)
union FusedSm {
    short sH[4][16 * LDH];                  // 17408 B (GEMM role)
    struct {                                // 26656 B (binA2 role)
        u64 recs[NBUCK][BCAP];
        int lcnt[NBUCK];
    } bin;
};

// ---------------------------------------------------------------------------
// prep: W (fp32,[k][n]) -> Wt (bf16,[n][k]); zero the 1-int overflow counter.
// cnt needs no zeroing (ebuild writes all nodes); arena is written fully
// (valid or sentinel) every run -> no stale-data hazard across iterations.
// ---------------------------------------------------------------------------
__global__ __launch_bounds__(256) void prep(
    const float* __restrict__ W, unsigned short* __restrict__ Wt,
    int* __restrict__ ovfc)
{
    int id = blockIdx.x * 256 + threadIdx.x;   // 64 blocks * 256 = 16384
    int k = id >> 7, n = id & 127;
    Wt[n * 128 + k] = f2bf(W[id]);
    if (id == 0) *ovfc = 0;
}

// ---------------------------------------------------------------------------
// GEMM half (measured 11us standalone, R11 probe) — unchanged.
// ---------------------------------------------------------------------------
__device__ __forceinline__ void gemm_body(
    int gid, int t,
    const float* __restrict__ x, const unsigned short* __restrict__ Wt,
    const float* __restrict__ att_src, const float* __restrict__ att_dst,
    unsigned short* __restrict__ h_out,
    float* __restrict__ a_src, float* __restrict__ a_dst,
    short (*sH)[16 * LDH])
{
    const int wv  = t >> 6;
    const int l   = t & 63;
    const int gw  = gid * 4 + wv;
    if (gw >= N_NODES / 16) return;            // 3125 active waves, no barriers

    const int n0   = gw * 16;
    const int mrow = l & 15;
    const int quad = l >> 4;

    short8 afrag[4];
    const float* xr = x + (size_t)(n0 + mrow) * IN_C + quad * 8;
#pragma unroll
    for (int ko = 0; ko < 4; ++ko) {
        float4 u = *reinterpret_cast<const float4*>(xr + ko * 32);
        float4 v = *reinterpret_cast<const float4*>(xr + ko * 32 + 4);
        afrag[ko] = pack8(u, v);
    }

    f32x4 acc[8];
#pragma unroll
    for (int nt = 0; nt < 8; ++nt) acc[nt] = (f32x4)0.f;
#pragma unroll
    for (int nt = 0; nt < 8; ++nt) {
        const unsigned short* wr = Wt + (nt * 16 + mrow) * 128 + quad * 8;
#pragma unroll
        for (int ko = 0; ko < 4; ++ko) {
            short8 bfr = *reinterpret_cast<const short8*>(wr + ko * 32);
            acc[nt] = __builtin_amdgcn_mfma_f32_16x16x32_bf16(afrag[ko], bfr, acc[nt], 0, 0, 0);
        }
    }

    // C -> per-wave LDS tile. C/D layout: col = lane&15, row = quad*4 + r.
#pragma unroll
    for (int nt = 0; nt < 8; ++nt)
#pragma unroll
        for (int r = 0; r < 4; ++r)
            sH[wv][(quad * 4 + r) * LDH + nt * 16 + mrow] = (short)f2bf(acc[nt][r]);
    // within-wave LDS write->read: lockstep + compiler lgkmcnt, no barrier

    // h store: 16 rows x 128 cols bf16, 16B per lane per iter
#pragma unroll
    for (int i = 0; i < 4; ++i) {
        int row = i * 4 + (l >> 4);
        int col = (l & 15) * 8;
        short8 hv = *reinterpret_cast<const short8*>(&sH[wv][row * LDH + col]);
        *reinterpret_cast<short8*>(h_out + (size_t)(n0 + row) * HC + col) = hv;
    }

    // a_src/a_dst: 128 (node,head) pairs per wave, 2 per lane
#pragma unroll
    for (int pp = 0; pp < 2; ++pp) {
        int p  = l + pp * 64;
        int m  = p >> 3;
        int hd = p & 7;
        float ssum = 0.f, dsum = 0.f;
#pragma unroll
        for (int c = 0; c < 16; ++c) {
            float hv = bf2f((unsigned short)sH[wv][m * LDH + hd * 16 + c]);
            ssum = fmaf(hv, att_src[hd * 16 + c], ssum);
            dsum = fmaf(hv, att_dst[hd * 16 + c], dsum);
        }
        a_src[(n0 + m) * HEADS + hd] = ssum;
        a_dst[(n0 + m) * HEADS + hd] = dsum;
    }
}

// ---------------------------------------------------------------------------
// fused: bid&1 split (champion form).
//   even -> GEMM. odd -> binA2 v2:
//   * 392 buckets of 128 nodes, BCAP=8 -> segment = one full 64B line.
//   * Segments written UNCONDITIONALLY (sentinel fills invalid slots) ->
//     pure full-line stores, zero partial-line memory RMW (R14's binA2
//     wrote ~84B of 208B segments -> residual RMW tax).
//   * No bcnt array: sentinel encodes validity.
//   * Zero global atomics (except ~460 expected overflow spills).
// ---------------------------------------------------------------------------
__global__ __launch_bounds__(256) void fused(
    const float* __restrict__ x, const unsigned short* __restrict__ Wt,
    const float* __restrict__ att_src, const float* __restrict__ att_dst,
    const int* __restrict__ ei, const float* __restrict__ edge_attr,
    u64* __restrict__ arena, int* __restrict__ ovfc, u64* __restrict__ ovf,
    unsigned short* __restrict__ h_out,
    float* __restrict__ a_src, float* __restrict__ a_dst)
{
    __shared__ FusedSm sm;
    const int bid = blockIdx.x;
    const int t   = threadIdx.x;

    if (bid & 1) {
        // ---------------- binA2 v2 ----------------
        const int blk = bid >> 1;              // 0..781
        for (int i = t; i < NBUCK; i += 256) sm.bin.lcnt[i] = 0;
        __syncthreads();

        const int e0 = blk * 1024 + t * 4;
        if (e0 < N_EDGES) {                    // N_EDGES%4==0 -> int4 safe
            const int4   s4 = *reinterpret_cast<const int4*>(ei + e0);
            const int4   d4 = *reinterpret_cast<const int4*>(ei + N_EDGES + e0);
            const float4 a4 = *reinterpret_cast<const float4*>(edge_attr + e0);
#define BIN1(D, S, A)                                                      \
            {                                                              \
                const unsigned w_ =                                        \
                    (((unsigned)(S)) << 16) | (unsigned)f2bf(A);           \
                const int b_ = (D) >> 7;                                   \
                int p_ = atomicAdd(&sm.bin.lcnt[b_], 1);                   \
                if (p_ < BCAP)                                             \
                    sm.bin.recs[b_][p_] =                                  \
                        ((u64)(unsigned)((D) & 127) << 32) | (u64)w_;      \
                else {                                                     \
                    int op_ = atomicAdd(ovfc, 1);                          \
                    if (op_ < OVF_CAP)                                     \
                        ovf[op_] = ((u64)(unsigned)(D) << 32) | (u64)w_;   \
                }                                                          \
            }
            BIN1(d4.x, s4.x, a4.x)
            BIN1(d4.y, s4.y, a4.y)
            BIN1(d4.z, s4.z, a4.z)
            BIN1(d4.w, s4.w, a4.w)
#undef BIN1
        }
        __syncthreads();
        // LDS runs -> static arena segments. Write ALL slots (sentinel for
        // invalid) -> every 64B line fully written, no memory-side RMW.
        for (int i = t; i < NBUCK * BCAP; i += 256) {
            const int bi = i >> 3;
            const int j  = i & 7;
            u64 v = (j < sm.bin.lcnt[bi]) ? sm.bin.recs[bi][j] : SENT;
            arena[((size_t)bi * FILL_BLOCKS + blk) * BCAP + j] = v;
        }
        return;
    }

    gemm_body(bid >> 1, t, x, Wt, att_src, att_dst, h_out, a_src, a_dst, sm.sH);
}

// ---------------------------------------------------------------------------
// ebuild: 392 blocks x 256 threads (full machine; R14's 98x1024 covered only
// ~38% of CUs). Each block owns one 128-node bucket: linear coalesced scan
// of its contiguous 50KB segment strip (19.6MB total, read exactly once),
// ELL slots via 128 LDS cursors, ellp/cnt written with normal stores —
// single-writer lines, and each node's ~16 entries fill one 64B line.
// ---------------------------------------------------------------------------
__global__ __launch_bounds__(256) void ebuild(
    const u64* __restrict__ arena, const int* __restrict__ ovfc,
    const u64* __restrict__ ovf,
    unsigned int* __restrict__ ellp, int* __restrict__ cnt)
{
    __shared__ int lc[128];
    const int t = threadIdx.x;
    const int b = blockIdx.x;                  // bucket 0..391
    if (t < 128) lc[t] = 0;
    __syncthreads();

    const u64* seg = arena + (size_t)b * (FILL_BLOCKS * BCAP);
    for (int q = t; q < FILL_BLOCKS * BCAP; q += 256) {   // 6256/256 ~ 24 it
        const u64 rec = seg[q];                // coalesced: linear in q
        if (rec != SENT) {
            const int dl = (int)(rec >> 32);   // 0..127
            int p = atomicAdd(&lc[dl], 1);
            if (p < ELL_CAP)
                ellp[((size_t)((b << 7) + dl) << 6) + p] = (unsigned)rec;
        }
    }
    // spill entries (expected ~460): every block scans, keeps its own
    const int ovn = min(*ovfc, OVF_CAP);
    for (int q = t; q < ovn; q += 256) {
        const u64 rec = ovf[q];
        const int n = (int)(rec >> 32);
        if ((n >> 7) == b) {
            int p = atomicAdd(&lc[n & 127], 1);
            if (p < ELL_CAP)
                ellp[((size_t)n << 6) + p] = (unsigned)rec;
        }
    }
    __syncthreads();
    if (t < 128) {
        const int n = (b << 7) + t;
        if (n < N_NODES) cnt[n] = min(lc[t], ELL_CAP);
    }
}

// ---------------------------------------------------------------------------
// gather: byte-identical to the 188us champion.
// ---------------------------------------------------------------------------

// swizzle offset (j<<5)|24: lane' = (lane & 56) | j  (broadcast within the
// 8-lane head group; bit 5 preserved by per-32-lane ds_swizzle semantics)
#define LROW(CE, HV, J, OFF, B0)                                           \
    { int cj_ = __builtin_amdgcn_ds_swizzle((int)(CE), OFF);               \
      size_t r_ = ((B0) + (J) < cn) ? (size_t)(((unsigned)cj_) >> 16) : 0; \
      (HV)[J] = h2[r_ * 64 + l]; }
#define LOADROWS(CE, HV, B0)                                               \
    LROW(CE, HV, 0,  24, B0) LROW(CE, HV, 1,  56, B0)                      \
    LROW(CE, HV, 2,  88, B0) LROW(CE, HV, 3, 120, B0)                      \
    LROW(CE, HV, 4, 152, B0) LROW(CE, HV, 5, 184, B0)                      \
    LROW(CE, HV, 6, 216, B0) LROW(CE, HV, 7, 248, B0)

#define FROW(EV, HV, J, OFF)                                               \
    { float evj_ = __uint_as_float((unsigned)__builtin_amdgcn_ds_swizzle(  \
          __float_as_int(EV), OFF));                                       \
      acc0 = fmaf(evj_, b2f((HV)[J].x), acc0);                             \
      acc1 = fmaf(evj_, b2f((HV)[J].y), acc1); }
#define FMAROWS(EV, HV)                                                    \
    FROW(EV, HV, 0,  24) FROW(EV, HV, 1,  56) FROW(EV, HV, 2,  88)        \
    FROW(EV, HV, 3, 120) FROW(EV, HV, 4, 152) FROW(EV, HV, 5, 184)        \
    FROW(EV, HV, 6, 216) FROW(EV, HV, 7, 248)

__global__ __launch_bounds__(256) void gather_node(
    const int* __restrict__ cnt, const unsigned int* __restrict__ ellp,
    const float* __restrict__ a_src, const float* __restrict__ a_dst,
    const bf16* __restrict__ h,
    const float* __restrict__ x, const float* __restrict__ bvec,
    const float* __restrict__ gamma, const float* __restrict__ beta,
    const float* __restrict__ att_edge, const float* __restrict__ lin_w,
    const float* __restrict__ lin_b,
    float* __restrict__ out)
{
    const int wave = threadIdx.x >> 6;
    const int l    = threadIdx.x & 63;
    const int n    = blockIdx.x * 4 + wave;       // 50000 % 4 == 0
    const int hh   = l >> 3;
    const int jj   = l & 7;

    float ae0 = att_edge[2 * l], ae1 = att_edge[2 * l + 1];
    float p = ae0 * lin_w[2 * l] + ae1 * lin_w[2 * l + 1];
    float q = ae0 * lin_b[2 * l] + ae1 * lin_b[2 * l + 1];
#pragma unroll
    for (int off = 1; off <= 4; off <<= 1) {
        p += __shfl_xor(p, off, 64);
        q += __shfl_xor(q, off, 64);
    }
    const float2 bv = *reinterpret_cast<const float2*>(bvec + 2 * l);
    const float2 gv = *reinterpret_cast<const float2*>(gamma + 2 * l);
    const float2 be = *reinterpret_cast<const float2*>(beta + 2 * l);

    const float adq = a_dst[n * HEADS + hh] + q;
    const int   beg = n << 6;
    const int   cn  = min(cnt[n], ELL_CAP);

    float zp = 0.f, acc0 = 0.f, acc1 = 0.f;
    const __hip_bfloat162* h2 = reinterpret_cast<const __hip_bfloat162*>(h);

    if (cn > 0) {
        // pipeline prologue: chunk 0's ell word, a_src, and 8 h rows
        unsigned ce_c = ellp[beg + jj];
        float    as_c = a_src[(ce_c >> 16) * HEADS + hh];
        __hip_bfloat162 hv_c[8], hv_n[8];
        LOADROWS(ce_c, hv_c, 0)

        for (int bs = 0; ; bs += 8) {
            const unsigned ce   = ce_c;
            const float    as   = as_c;
            const bool     last = (bs + 8 >= cn);   // wave-uniform
            if (!last) {
                // issue next chunk's loads BEFORE this chunk's compute:
                // 8 h-rows + a_src stay in flight across the FMA block
                ce_c = ellp[beg + bs + 8 + jj];
                LOADROWS(ce_c, hv_n, bs + 8)
                as_c = a_src[(ce_c >> 16) * HEADS + hh];
            }
            const float ea = bf2f(ce & 0xffffu);
            float lg = fmaf(ea, p, as + adq);
            lg = fmaxf(lg, NEG_SLOPE * lg);         // leaky_relu, branchless
            const float ev = (bs + jj < cn) ? __expf(lg) : 0.f;
            zp += ev;
            FMAROWS(ev, hv_c)
            if (last) break;
#pragma unroll
            for (int j = 0; j < 8; ++j) hv_c[j] = hv_n[j];
        }
    }

    // z: reduce per-lane partials across the 8 lanes of this head group
    float z = zp;
    z += __shfl_xor(z, 1, 64);
    z += __shfl_xor(z, 2, 64);
    z += __shfl_xor(z, 4, 64);
    const float rz = 1.f / (z + 1e-16f);
    acc0 *= rz;
    acc1 *= rz;

    const size_t idx = (size_t)n * HC + 2 * l;
    const float2 xv = *reinterpret_cast<const float2*>(x + idx);
    float v0 = acc0 + xv.x + bv.x;
    float v1 = acc1 + xv.y + bv.y;
    float s1 = v0 + v1, s2 = v0 * v0 + v1 * v1;
#pragma unroll
    for (int off = 32; off >= 1; off >>= 1) {
        s1 += __shfl_xor(s1, off, 64);
        s2 += __shfl_xor(s2, off, 64);
    }
    const float mean = s1 * (1.f / HC);
    const float var  = s2 * (1.f / HC) - mean * mean;
    const float inv  = rsqrtf(var + LN_EPS);
    float y0 = (v0 - mean) * inv * gv.x + be.x;
    float y1 = (v1 - mean) * inv * gv.y + be.y;
    y0 = y0 > 0.f ? y0 : expm1f(y0);
    y1 = y1 > 0.f ? y1 : expm1f(y1);
    *reinterpret_cast<float2*>(out + idx) = make_float2(y0, y1);
}

// ---------------------------------------------------------------------------
extern "C" void kernel_launch(void* const* d_in, const int* in_sizes, int n_in,
                              void* d_out, int out_size, void* d_ws, size_t ws_size,
                              hipStream_t stream)
{
    const float* x         = (const float*)d_in[0];
    const int*   ei        = (const int*)d_in[1];
    const float* edge_attr = (const float*)d_in[2];
    const float* W         = (const float*)d_in[3];
    const float* b         = (const float*)d_in[4];
    const float* att_src   = (const float*)d_in[5];
    const float* att_dst   = (const float*)d_in[6];
    const float* att_edge  = (const float*)d_in[7];
    const float* lin_w     = (const float*)d_in[8];
    const float* lin_b     = (const float*)d_in[9];
    const float* gamma     = (const float*)d_in[10];
    const float* beta      = (const float*)d_in[11];

    char* ws = (char*)d_ws;
    bf16*  h     = (bf16*)ws;  ws += (size_t)N_NODES * HC * sizeof(bf16);      // 12.8 MB
    float* a_src = (float*)ws; ws += (size_t)N_NODES * HEADS * sizeof(float);  //  1.6 MB
    float* a_dst = (float*)ws; ws += (size_t)N_NODES * HEADS * sizeof(float);  //  1.6 MB
    int*   cnt   = (int*)ws;   ws += (size_t)N_NODES * sizeof(int);            //  0.2 MB
    unsigned short* Wt = (unsigned short*)ws;
    ws += (size_t)128 * 128 * sizeof(unsigned short);                          //  32 KB
    unsigned int* ellp = (unsigned int*)ws;
    ws += (size_t)(N_NODES * ELL_CAP + 64) * sizeof(unsigned int);             // 12.8 MB + pad
    int* ovfc = (int*)ws;      ws += 64;                                       // 64 B (pad)
    u64* ovf  = (u64*)ws;      ws += (size_t)OVF_CAP * sizeof(u64);            //  64 KB
    // arena (19.6 MB) lives in d_out (25.6 MB): consumed by ebuild BEFORE
    // gather overwrites d_out with the real output.
    u64* arena = (u64*)d_out;

    prep<<<64, 256, 0, stream>>>(W, Wt, ovfc);

    fused<<<FUSED_BLOCKS, 256, 0, stream>>>(
        x, Wt, att_src, att_dst, ei, edge_attr, arena, ovfc, ovf,
        (unsigned short*)h, a_src, a_dst);

    ebuild<<<NBUCK, 256, 0, stream>>>(arena, ovfc, ovf, ellp, cnt);

    gather_node<<<N_NODES / 4, 256, 0, stream>>>(
        cnt, ellp, a_src, a_dst, h, x, b, gamma, beta,
        att_edge, lin_w, lin_b, (float*)d_out);
}

// Round 18
// 186.541 us; speedup vs baseline: 1.4222x; 1.0260x over previous
//
#include <hip/hip_runtime.h>
#include <hip/hip_bf16.h>

#define N_NODES 50000
#define N_EDGES 800000
#define IN_C 128
#define HC 128
#define HEADS 8
#define NEG_SLOPE 0.2f
#define LN_EPS 1e-5f

#define LDH 136                 // per-wave h-tile row stride (128 + 8 pad)
#define ELL_CAP 64              // slots per node; max degree ~40 (Poisson 16)
#define GEMM_BLOCKS 782
#define FILL_BLOCKS 782
#define FUSED_BLOCKS (GEMM_BLOCKS + FILL_BLOCKS)   // 1564, champion form
#define NBUCK 392               // dst buckets of 128 nodes (392*128 = 50176)
#define BCAP 8                  // segment = exactly one 64B line; lambda 2.6
#define OVF_CAP 8192            // global spill (expect ~460 entries)
#define SENT 0xFFFFFFFFFFFFFFFFull

typedef __hip_bfloat16 bf16;
typedef __attribute__((ext_vector_type(8))) short short8;
typedef __attribute__((ext_vector_type(4))) float f32x4;
typedef unsigned long long u64;

__device__ __forceinline__ float b2f(bf16 v) { return __bfloat162float(v); }

// float -> bf16 bits, round-to-nearest-even
__device__ __forceinline__ unsigned short f2bf(float f) {
    unsigned u = __float_as_uint(f);
    return (unsigned short)((u + 0x7fffu + ((u >> 16) & 1u)) >> 16);
}
__device__ __forceinline__ float bf2f(unsigned s) {
    return __uint_as_float(s << 16);
}
__device__ __forceinline__ short8 pack8(float4 u, float4 v) {
    short8 r;
    r[0] = (short)f2bf(u.x); r[1] = (short)f2bf(u.y);
    r[2] = (short)f2bf(u.z); r[3] = (short)f2bf(u.w);
    r[4] = (short)f2bf(v.x); r[5] = (short)f2bf(v.y);
    r[6] = (short)f2bf(v.z); r[7] = (short)f2bf(v.w);
    return r;
}

// LDS layout for fused (union of the two roles)
union FusedSm {
    short sH[4][16 * LDH];                  // 17408 B (GEMM role)
    struct {                                // 26656 B (binA2 role)
        u64 recs[NBUCK][BCAP];
        int lcnt[NBUCK];
    } bin;
};

// ---------------------------------------------------------------------------
// prep: W (fp32,[k][n]) -> Wt (bf16,[n][k]); zero the 1-int overflow counter.
// cnt needs no zeroing (ebuild writes all nodes); arena is written fully
// (valid or sentinel) every run -> no stale-data hazard across iterations.
// ---------------------------------------------------------------------------
__global__ __launch_bounds__(256) void prep(
    const float* __restrict__ W, unsigned short* __restrict__ Wt,
    int* __restrict__ ovfc)
{
    int id = blockIdx.x * 256 + threadIdx.x;   // 64 blocks * 256 = 16384
    int k = id >> 7, n = id & 127;
    Wt[n * 128 + k] = f2bf(W[id]);
    if (id == 0) *ovfc = 0;
}

// ---------------------------------------------------------------------------
// GEMM half (measured 11us standalone, R11 probe) — unchanged.
// ---------------------------------------------------------------------------
__device__ __forceinline__ void gemm_body(
    int gid, int t,
    const float* __restrict__ x, const unsigned short* __restrict__ Wt,
    const float* __restrict__ att_src, const float* __restrict__ att_dst,
    unsigned short* __restrict__ h_out,
    float* __restrict__ a_src, float* __restrict__ a_dst,
    short (*sH)[16 * LDH])
{
    const int wv  = t >> 6;
    const int l   = t & 63;
    const int gw  = gid * 4 + wv;
    if (gw >= N_NODES / 16) return;            // 3125 active waves, no barriers

    const int n0   = gw * 16;
    const int mrow = l & 15;
    const int quad = l >> 4;

    short8 afrag[4];
    const float* xr = x + (size_t)(n0 + mrow) * IN_C + quad * 8;
#pragma unroll
    for (int ko = 0; ko < 4; ++ko) {
        float4 u = *reinterpret_cast<const float4*>(xr + ko * 32);
        float4 v = *reinterpret_cast<const float4*>(xr + ko * 32 + 4);
        afrag[ko] = pack8(u, v);
    }

    f32x4 acc[8];
#pragma unroll
    for (int nt = 0; nt < 8; ++nt) acc[nt] = (f32x4)0.f;
#pragma unroll
    for (int nt = 0; nt < 8; ++nt) {
        const unsigned short* wr = Wt + (nt * 16 + mrow) * 128 + quad * 8;
#pragma unroll
        for (int ko = 0; ko < 4; ++ko) {
            short8 bfr = *reinterpret_cast<const short8*>(wr + ko * 32);
            acc[nt] = __builtin_amdgcn_mfma_f32_16x16x32_bf16(afrag[ko], bfr, acc[nt], 0, 0, 0);
        }
    }

    // C -> per-wave LDS tile. C/D layout: col = lane&15, row = quad*4 + r.
#pragma unroll
    for (int nt = 0; nt < 8; ++nt)
#pragma unroll
        for (int r = 0; r < 4; ++r)
            sH[wv][(quad * 4 + r) * LDH + nt * 16 + mrow] = (short)f2bf(acc[nt][r]);
    // within-wave LDS write->read: lockstep + compiler lgkmcnt, no barrier

    // h store: 16 rows x 128 cols bf16, 16B per lane per iter
#pragma unroll
    for (int i = 0; i < 4; ++i) {
        int row = i * 4 + (l >> 4);
        int col = (l & 15) * 8;
        short8 hv = *reinterpret_cast<const short8*>(&sH[wv][row * LDH + col]);
        *reinterpret_cast<short8*>(h_out + (size_t)(n0 + row) * HC + col) = hv;
    }

    // a_src/a_dst: 128 (node,head) pairs per wave, 2 per lane
#pragma unroll
    for (int pp = 0; pp < 2; ++pp) {
        int p  = l + pp * 64;
        int m  = p >> 3;
        int hd = p & 7;
        float ssum = 0.f, dsum = 0.f;
#pragma unroll
        for (int c = 0; c < 16; ++c) {
            float hv = bf2f((unsigned short)sH[wv][m * LDH + hd * 16 + c]);
            ssum = fmaf(hv, att_src[hd * 16 + c], ssum);
            dsum = fmaf(hv, att_dst[hd * 16 + c], dsum);
        }
        a_src[(n0 + m) * HEADS + hd] = ssum;
        a_dst[(n0 + m) * HEADS + hd] = dsum;
    }
}

// ---------------------------------------------------------------------------
// fused: bid&1 split (champion form). Byte-identical to R15.
//   even -> GEMM. odd -> binA2: LDS-binned edges -> static full-line arena
//   segments (sentinel-padded), zero global atomics, zero contended counters.
// ---------------------------------------------------------------------------
__global__ __launch_bounds__(256) void fused(
    const float* __restrict__ x, const unsigned short* __restrict__ Wt,
    const float* __restrict__ att_src, const float* __restrict__ att_dst,
    const int* __restrict__ ei, const float* __restrict__ edge_attr,
    u64* __restrict__ arena, int* __restrict__ ovfc, u64* __restrict__ ovf,
    unsigned short* __restrict__ h_out,
    float* __restrict__ a_src, float* __restrict__ a_dst)
{
    __shared__ FusedSm sm;
    const int bid = blockIdx.x;
    const int t   = threadIdx.x;

    if (bid & 1) {
        // ---------------- binA2 ----------------
        const int blk = bid >> 1;              // 0..781
        for (int i = t; i < NBUCK; i += 256) sm.bin.lcnt[i] = 0;
        __syncthreads();

        const int e0 = blk * 1024 + t * 4;
        if (e0 < N_EDGES) {                    // N_EDGES%4==0 -> int4 safe
            const int4   s4 = *reinterpret_cast<const int4*>(ei + e0);
            const int4   d4 = *reinterpret_cast<const int4*>(ei + N_EDGES + e0);
            const float4 a4 = *reinterpret_cast<const float4*>(edge_attr + e0);
#define BIN1(D, S, A)                                                      \
            {                                                              \
                const unsigned w_ =                                        \
                    (((unsigned)(S)) << 16) | (unsigned)f2bf(A);           \
                const int b_ = (D) >> 7;                                   \
                int p_ = atomicAdd(&sm.bin.lcnt[b_], 1);                   \
                if (p_ < BCAP)                                             \
                    sm.bin.recs[b_][p_] =                                  \
                        ((u64)(unsigned)((D) & 127) << 32) | (u64)w_;      \
                else {                                                     \
                    int op_ = atomicAdd(ovfc, 1);                          \
                    if (op_ < OVF_CAP)                                     \
                        ovf[op_] = ((u64)(unsigned)(D) << 32) | (u64)w_;   \
                }                                                          \
            }
            BIN1(d4.x, s4.x, a4.x)
            BIN1(d4.y, s4.y, a4.y)
            BIN1(d4.z, s4.z, a4.z)
            BIN1(d4.w, s4.w, a4.w)
#undef BIN1
        }
        __syncthreads();
        // LDS runs -> static arena segments. Write ALL slots (sentinel for
        // invalid) -> every 64B line fully written, no memory-side RMW.
        for (int i = t; i < NBUCK * BCAP; i += 256) {
            const int bi = i >> 3;
            const int j  = i & 7;
            u64 v = (j < sm.bin.lcnt[bi]) ? sm.bin.recs[bi][j] : SENT;
            arena[((size_t)bi * FILL_BLOCKS + blk) * BCAP + j] = v;
        }
        return;
    }

    gemm_body(bid >> 1, t, x, Wt, att_src, att_dst, h_out, a_src, a_dst, sm.sH);
}

// ---------------------------------------------------------------------------
// ebuild v2: 392 blocks x 512 threads. THE LAST SCATTERED-4B-STORE SITE IS
// REMOVED: the bucket's whole ELL table (128 nodes x 64 slots = 32KB) is
// assembled in LDS (LDS atomics for slot assignment), then streamed to
// global as contiguous full-line uint4 stores. R3/R14/R15 all performed
// 800k scattered 4B global stores somewhere (fill or ebuild) and all landed
// at the same total — that scatter is the invariant this removes. Slots
// beyond a node's cn carry garbage; gather masks by cn (same contract).
// ---------------------------------------------------------------------------
__global__ __launch_bounds__(512) void ebuild(
    const u64* __restrict__ arena, const int* __restrict__ ovfc,
    const u64* __restrict__ ovf,
    unsigned int* __restrict__ ellp, int* __restrict__ cnt)
{
    __shared__ unsigned int ell[128 * ELL_CAP];   // 32 KB
    __shared__ int lc[128];
    const int t = threadIdx.x;
    const int b = blockIdx.x;                  // bucket 0..391
    if (t < 128) lc[t] = 0;
    __syncthreads();

    const u64* seg = arena + (size_t)b * (FILL_BLOCKS * BCAP);
    for (int q = t; q < FILL_BLOCKS * BCAP; q += 512) {   // 6256/512 ~ 12 it
        const u64 rec = seg[q];                // coalesced: linear in q
        if (rec != SENT) {
            const int dl = (int)(rec >> 32);   // 0..127
            int p = atomicAdd(&lc[dl], 1);
            if (p < ELL_CAP) ell[(dl << 6) + p] = (unsigned)rec;
        }
    }
    // spill entries (expected ~460): every block scans, keeps its own
    const int ovn = min(*ovfc, OVF_CAP);
    for (int q = t; q < ovn; q += 512) {
        const u64 rec = ovf[q];
        const int n = (int)(rec >> 32);
        if ((n >> 7) == b) {
            int p = atomicAdd(&lc[n & 127], 1);
            if (p < ELL_CAP) ell[((n & 127) << 6) + p] = (unsigned)rec;
        }
    }
    __syncthreads();
    // full-line streamed write: 32 KB contiguous per block, uint4 stores
    uint4* eg = reinterpret_cast<uint4*>(ellp + ((size_t)b << 13));
    const uint4* es = reinterpret_cast<const uint4*>(ell);
#pragma unroll
    for (int q = t; q < 128 * ELL_CAP / 4; q += 512) eg[q] = es[q];
    if (t < 128) {
        const int n = (b << 7) + t;
        if (n < N_NODES) cnt[n] = min(lc[t], ELL_CAP);
    }
}

// ---------------------------------------------------------------------------
// gather: byte-identical to the 188us champion.
// ---------------------------------------------------------------------------

// swizzle offset (j<<5)|24: lane' = (lane & 56) | j  (broadcast within the
// 8-lane head group; bit 5 preserved by per-32-lane ds_swizzle semantics)
#define LROW(CE, HV, J, OFF, B0)                                           \
    { int cj_ = __builtin_amdgcn_ds_swizzle((int)(CE), OFF);               \
      size_t r_ = ((B0) + (J) < cn) ? (size_t)(((unsigned)cj_) >> 16) : 0; \
      (HV)[J] = h2[r_ * 64 + l]; }
#define LOADROWS(CE, HV, B0)                                               \
    LROW(CE, HV, 0,  24, B0) LROW(CE, HV, 1,  56, B0)                      \
    LROW(CE, HV, 2,  88, B0) LROW(CE, HV, 3, 120, B0)                      \
    LROW(CE, HV, 4, 152, B0) LROW(CE, HV, 5, 184, B0)                      \
    LROW(CE, HV, 6, 216, B0) LROW(CE, HV, 7, 248, B0)

#define FROW(EV, HV, J, OFF)                                               \
    { float evj_ = __uint_as_float((unsigned)__builtin_amdgcn_ds_swizzle(  \
          __float_as_int(EV), OFF));                                       \
      acc0 = fmaf(evj_, b2f((HV)[J].x), acc0);                             \
      acc1 = fmaf(evj_, b2f((HV)[J].y), acc1); }
#define FMAROWS(EV, HV)                                                    \
    FROW(EV, HV, 0,  24) FROW(EV, HV, 1,  56) FROW(EV, HV, 2,  88)        \
    FROW(EV, HV, 3, 120) FROW(EV, HV, 4, 152) FROW(EV, HV, 5, 184)        \
    FROW(EV, HV, 6, 216) FROW(EV, HV, 7, 248)

__global__ __launch_bounds__(256) void gather_node(
    const int* __restrict__ cnt, const unsigned int* __restrict__ ellp,
    const float* __restrict__ a_src, const float* __restrict__ a_dst,
    const bf16* __restrict__ h,
    const float* __restrict__ x, const float* __restrict__ bvec,
    const float* __restrict__ gamma, const float* __restrict__ beta,
    const float* __restrict__ att_edge, const float* __restrict__ lin_w,
    const float* __restrict__ lin_b,
    float* __restrict__ out)
{
    const int wave = threadIdx.x >> 6;
    const int l    = threadIdx.x & 63;
    const int n    = blockIdx.x * 4 + wave;       // 50000 % 4 == 0
    const int hh   = l >> 3;
    const int jj   = l & 7;

    float ae0 = att_edge[2 * l], ae1 = att_edge[2 * l + 1];
    float p = ae0 * lin_w[2 * l] + ae1 * lin_w[2 * l + 1];
    float q = ae0 * lin_b[2 * l] + ae1 * lin_b[2 * l + 1];
#pragma unroll
    for (int off = 1; off <= 4; off <<= 1) {
        p += __shfl_xor(p, off, 64);
        q += __shfl_xor(q, off, 64);
    }
    const float2 bv = *reinterpret_cast<const float2*>(bvec + 2 * l);
    const float2 gv = *reinterpret_cast<const float2*>(gamma + 2 * l);
    const float2 be = *reinterpret_cast<const float2*>(beta + 2 * l);

    const float adq = a_dst[n * HEADS + hh] + q;
    const int   beg = n << 6;
    const int   cn  = min(cnt[n], ELL_CAP);

    float zp = 0.f, acc0 = 0.f, acc1 = 0.f;
    const __hip_bfloat162* h2 = reinterpret_cast<const __hip_bfloat162*>(h);

    if (cn > 0) {
        // pipeline prologue: chunk 0's ell word, a_src, and 8 h rows
        unsigned ce_c = ellp[beg + jj];
        float    as_c = a_src[(ce_c >> 16) * HEADS + hh];
        __hip_bfloat162 hv_c[8], hv_n[8];
        LOADROWS(ce_c, hv_c, 0)

        for (int bs = 0; ; bs += 8) {
            const unsigned ce   = ce_c;
            const float    as   = as_c;
            const bool     last = (bs + 8 >= cn);   // wave-uniform
            if (!last) {
                // issue next chunk's loads BEFORE this chunk's compute:
                // 8 h-rows + a_src stay in flight across the FMA block
                ce_c = ellp[beg + bs + 8 + jj];
                LOADROWS(ce_c, hv_n, bs + 8)
                as_c = a_src[(ce_c >> 16) * HEADS + hh];
            }
            const float ea = bf2f(ce & 0xffffu);
            float lg = fmaf(ea, p, as + adq);
            lg = fmaxf(lg, NEG_SLOPE * lg);         // leaky_relu, branchless
            const float ev = (bs + jj < cn) ? __expf(lg) : 0.f;
            zp += ev;
            FMAROWS(ev, hv_c)
            if (last) break;
#pragma unroll
            for (int j = 0; j < 8; ++j) hv_c[j] = hv_n[j];
        }
    }

    // z: reduce per-lane partials across the 8 lanes of this head group
    float z = zp;
    z += __shfl_xor(z, 1, 64);
    z += __shfl_xor(z, 2, 64);
    z += __shfl_xor(z, 4, 64);
    const float rz = 1.f / (z + 1e-16f);
    acc0 *= rz;
    acc1 *= rz;

    const size_t idx = (size_t)n * HC + 2 * l;
    const float2 xv = *reinterpret_cast<const float2*>(x + idx);
    float v0 = acc0 + xv.x + bv.x;
    float v1 = acc1 + xv.y + bv.y;
    float s1 = v0 + v1, s2 = v0 * v0 + v1 * v1;
#pragma unroll
    for (int off = 32; off >= 1; off >>= 1) {
        s1 += __shfl_xor(s1, off, 64);
        s2 += __shfl_xor(s2, off, 64);
    }
    const float mean = s1 * (1.f / HC);
    const float var  = s2 * (1.f / HC) - mean * mean;
    const float inv  = rsqrtf(var + LN_EPS);
    float y0 = (v0 - mean) * inv * gv.x + be.x;
    float y1 = (v1 - mean) * inv * gv.y + be.y;
    y0 = y0 > 0.f ? y0 : expm1f(y0);
    y1 = y1 > 0.f ? y1 : expm1f(y1);
    *reinterpret_cast<float2*>(out + idx) = make_float2(y0, y1);
}

// ---------------------------------------------------------------------------
extern "C" void kernel_launch(void* const* d_in, const int* in_sizes, int n_in,
                              void* d_out, int out_size, void* d_ws, size_t ws_size,
                              hipStream_t stream)
{
    const float* x         = (const float*)d_in[0];
    const int*   ei        = (const int*)d_in[1];
    const float* edge_attr = (const float*)d_in[2];
    const float* W         = (const float*)d_in[3];
    const float* b         = (const float*)d_in[4];
    const float* att_src   = (const float*)d_in[5];
    const float* att_dst   = (const float*)d_in[6];
    const float* att_edge  = (const float*)d_in[7];
    const float* lin_w     = (const float*)d_in[8];
    const float* lin_b     = (const float*)d_in[9];
    const float* gamma     = (const float*)d_in[10];
    const float* beta      = (const float*)d_in[11];

    char* ws = (char*)d_ws;
    bf16*  h     = (bf16*)ws;  ws += (size_t)N_NODES * HC * sizeof(bf16);      // 12.8 MB
    float* a_src = (float*)ws; ws += (size_t)N_NODES * HEADS * sizeof(float);  //  1.6 MB
    float* a_dst = (float*)ws; ws += (size_t)N_NODES * HEADS * sizeof(float);  //  1.6 MB
    int*   cnt   = (int*)ws;   ws += (size_t)N_NODES * sizeof(int);            //  0.2 MB
    unsigned short* Wt = (unsigned short*)ws;
    ws += (size_t)128 * 128 * sizeof(unsigned short);                          //  32 KB
    unsigned int* ellp = (unsigned int*)ws;
    ws += (size_t)(NBUCK * 128 * ELL_CAP + 64) * sizeof(unsigned int);         // 12.85 MB + pad
    int* ovfc = (int*)ws;      ws += 64;                                       // 64 B (pad)
    u64* ovf  = (u64*)ws;      ws += (size_t)OVF_CAP * sizeof(u64);            //  64 KB
    // arena (19.6 MB) lives in d_out (25.6 MB): consumed by ebuild BEFORE
    // gather overwrites d_out with the real output.
    u64* arena = (u64*)d_out;

    prep<<<64, 256, 0, stream>>>(W, Wt, ovfc);

    fused<<<FUSED_BLOCKS, 256, 0, stream>>>(
        x, Wt, att_src, att_dst, ei, edge_attr, arena, ovfc, ovf,
        (unsigned short*)h, a_src, a_dst);

    ebuild<<<NBUCK, 512, 0, stream>>>(arena, ovfc, ovf, ellp, cnt);

    gather_node<<<N_NODES / 4, 256, 0, stream>>>(
        cnt, ellp, a_src, a_dst, h, x, b, gamma, beta,
        att_edge, lin_w, lin_b, (float*)d_out);
}